// Round 1
// baseline (1328.671 us; speedup 1.0000x reference)
//
#include <hip/hip_runtime.h>

// TopK mask: out = x where x is among row's top-k (ties -> lowest index), else 0.
// x: [8192, 24576] fp32, k = 64 (read from device), out fp32 same shape.
//
// Strategy: one 1024-thread block per row; 24 elems/thread held in VGPRs
// (single global read), 4-pass 256-bin MSB radix select in LDS for the exact
// k-th largest, then masked nontemporal write. Traffic = 1 read + 1 write.

#define COLS  24576
#define TPB   1024
#define NCH   6            // float4 chunks per thread
#define EPT   24           // elements per thread
#define NSUB  32           // pass-0 sub-histograms (per wave x lane parity)
#define HPAD  257          // +1 padding: spreads sub-hist banks

typedef float v4f __attribute__((ext_vector_type(4)));

// order-preserving float->uint (ascending): topk by value == topk by u
__device__ __forceinline__ unsigned int f2o(unsigned int b) {
    return (b & 0x80000000u) ? ~b : (b | 0x80000000u);
}
__device__ __forceinline__ float o2f(unsigned int u) {
    unsigned int b = (u & 0x80000000u) ? (u & 0x7fffffffu) : ~u;
    return __uint_as_float(b);
}

extern "C" __global__ __launch_bounds__(TPB, 8)
void topk_mask(const float* __restrict__ x, const int* __restrict__ kptr,
               float* __restrict__ out)
{
    __shared__ unsigned int whist[NSUB * HPAD];  // 32.1 KiB, pass-0 only
    __shared__ unsigned int hist[256];
    __shared__ unsigned int sb, sr, scnt;

    const int t    = threadIdx.x;
    const int lane = t & 63;
    const int wave = t >> 6;
    const long long row = blockIdx.x;

    const unsigned int k = (unsigned int)kptr[0];

    // zero sub-histograms (independent of loads -> overlaps load latency)
    for (int i = t; i < NSUB * HPAD; i += TPB) whist[i] = 0u;

    // coalesced 16B/lane nontemporal loads; convert to ordered uints
    const v4f* rp = (const v4f*)(x + row * COLS);
    unsigned int uu[EPT];
    #pragma unroll
    for (int j = 0; j < NCH; j++) {
        v4f v = __builtin_nontemporal_load(rp + j * TPB + t);
        uu[4*j+0] = f2o(__float_as_uint(v.x));
        uu[4*j+1] = f2o(__float_as_uint(v.y));
        uu[4*j+2] = f2o(__float_as_uint(v.z));
        uu[4*j+3] = f2o(__float_as_uint(v.w));
    }
    __syncthreads();

    // ---- radix pass 0: bits [31:24]; skewed bins -> 32 sub-hists ----
    unsigned int* myh = &whist[(((unsigned)wave << 1) | (unsigned)(lane & 1)) * HPAD];
    #pragma unroll
    for (int e = 0; e < EPT; e++) atomicAdd(&myh[uu[e] >> 24], 1u);
    __syncthreads();

    if (t < 256) {  // combine 32 sub-hists
        unsigned int s = 0;
        #pragma unroll
        for (int h = 0; h < NSUB; h++) s += whist[h * HPAD + t];
        hist[t] = s;
    }
    __syncthreads();

    // wave-0 suffix-scan over 256 bins (4 bins/lane, high->low), finds the
    // bin where the cumulative count from the top crosses rr.
    auto scan_select = [&](unsigned int rr) {
        unsigned int c0 = hist[4*lane+0], c1 = hist[4*lane+1];
        unsigned int c2 = hist[4*lane+2], c3 = hist[4*lane+3];
        unsigned int gs = c0 + c1 + c2 + c3;
        unsigned int s = gs;
        #pragma unroll
        for (int d = 1; d < 64; d <<= 1) {
            unsigned int o = __shfl_down(s, d);
            s += (lane + d < 64) ? o : 0u;
        }
        unsigned int T = s - gs;               // sum over lanes > lane
        if (T < rr && rr <= T + gs) {          // exactly one lane true
            unsigned int A = T, b, c;
            if (A + c3 >= rr)                { b = 3; c = c3; }
            else if (A + c3 + c2 >= rr)      { A += c3;           b = 2; c = c2; }
            else if (A + c3 + c2 + c1 >= rr) { A += c3 + c2;      b = 1; c = c1; }
            else                             { A += c3 + c2 + c1; b = 0; c = c0; }
            sb   = 4u * (unsigned)lane + b;    // selected bin
            sr   = rr - A;                     // rank remaining inside bin
            scnt = c;                          // candidates in bin
        }
    };

    unsigned int r = k;
    if (wave == 0) scan_select(r);
    __syncthreads();
    unsigned int pref = sb;
    r = sr;

    // ---- radix passes 1..3: few candidates -> single shared hist ----
    #pragma unroll
    for (int shift = 16; shift >= 0; shift -= 8) {
        if (t < 256) hist[t] = 0u;
        __syncthreads();
        #pragma unroll
        for (int e = 0; e < EPT; e++) {
            unsigned int u = uu[e];
            if ((u >> (shift + 8)) == pref)
                atomicAdd(&hist[(u >> shift) & 255u], 1u);
        }
        __syncthreads();
        if (wave == 0) scan_select(r);
        __syncthreads();
        pref = (pref << 8) | sb;
        r = sr;
    }

    const unsigned int u_t  = pref;   // exact k-th largest (ordered encoding)
    const unsigned int need = r;      // #elements == u_t to include
    const unsigned int eq   = scnt;   // #elements == u_t total

    // Tie resolution (rare): smallest column cutoff m with
    // count(col < m && u == u_t) == need  -> lowest indices win (matches XLA).
    unsigned int m = COLS;
    if (eq != need) {
        unsigned int lo = 0, hi = COLS;
        while (hi - lo > 1u) {
            unsigned int mid = (lo + hi) >> 1;
            __syncthreads();
            if (t == 0) hist[0] = 0u;
            __syncthreads();
            unsigned int loc = 0;
            #pragma unroll
            for (int j = 0; j < NCH; j++) {
                #pragma unroll
                for (int q = 0; q < 4; q++) {
                    unsigned int col = (unsigned)(j * (TPB * 4) + (t << 2) + q);
                    loc += (uu[4*j+q] == u_t && col < mid) ? 1u : 0u;
                }
            }
            if (loc) atomicAdd(&hist[0], loc);
            __syncthreads();
            if (hist[0] >= need) hi = mid; else lo = mid;
        }
        m = hi;
    }

    // ---- masked write, nontemporal dwordx4 ----
    v4f* op = (v4f*)(out + row * COLS);
    #pragma unroll
    for (int j = 0; j < NCH; j++) {
        unsigned int cbase = (unsigned)(j * (TPB * 4) + (t << 2));
        unsigned int u0 = uu[4*j+0], u1 = uu[4*j+1];
        unsigned int u2 = uu[4*j+2], u3 = uu[4*j+3];
        v4f w;
        w.x = (u0 > u_t || (u0 == u_t && cbase + 0u < m)) ? o2f(u0) : 0.0f;
        w.y = (u1 > u_t || (u1 == u_t && cbase + 1u < m)) ? o2f(u1) : 0.0f;
        w.z = (u2 > u_t || (u2 == u_t && cbase + 2u < m)) ? o2f(u2) : 0.0f;
        w.w = (u3 > u_t || (u3 == u_t && cbase + 3u < m)) ? o2f(u3) : 0.0f;
        __builtin_nontemporal_store(w, op + j * TPB + t);
    }
}

extern "C" void kernel_launch(void* const* d_in, const int* in_sizes, int n_in,
                              void* d_out, int out_size, void* d_ws, size_t ws_size,
                              hipStream_t stream)
{
    const float* x    = (const float*)d_in[0];
    const int*   kptr = (const int*)d_in[1];
    float*       outp = (float*)d_out;
    const int rows = in_sizes[0] / COLS;   // 8192
    topk_mask<<<rows, TPB, 0, stream>>>(x, kptr, outp);
}